// Round 12
// baseline (467.994 us; speedup 1.0000x reference)
//
#include <hip/hip_runtime.h>

// GCN: 3x (GEMM -> normalized edge aggregation -> +self +bias +ReLU),
// then global mean pool over 64 graphs, then FC [128 -> 10].
// R7: (a) node_prep's single-cursor atomic (wave-serialized, 30ms spike seen
// in profile) replaced by a 3-dispatch exclusive scan of deg — zero atomics.
// (b) pull split into feature halves keyed to blockIdx parity: round-robin
// block->XCD dispatch means each XCD's L2 sees a 12.8MB gather footprint
// instead of 25.6MB (4MB private L2 per XCD).

#define N_NODES 50000
#define N_EDGES 600000
#define DIM 128      // IN == H == 128
#define OUT_DIM 10
#define N_GRAPHS 64
#define STRIP 128    // pool rows per block
#define GR 64        // gemm rows per block
#define SCAN_G ((N_NODES + 255) / 256)   // 196 scan blocks

__global__ void zero_kernel(int* __restrict__ p, int n) {
    int i = blockIdx.x * blockDim.x + threadIdx.x;
    for (; i < n; i += gridDim.x * blockDim.x) p[i] = 0;
}

// in-degree histogram over dst (random addresses across 200KB, L2-resident)
__global__ void hist_kernel(const int* __restrict__ dst, int* __restrict__ deg) {
    int e = blockIdx.x * blockDim.x + threadIdx.x;
    if (e < N_EDGES) atomicAdd(&deg[dst[e]], 1);
}

// --- exclusive prefix sum of deg (3 dispatches, no atomics) ---
__global__ __launch_bounds__(256) void scan_local_kernel(const int* __restrict__ deg,
                                                         int* __restrict__ locx,
                                                         int* __restrict__ bsum,
                                                         float* __restrict__ dinv,
                                                         float* __restrict__ invdeg) {
    __shared__ int lds[256];
    int tid = threadIdx.x;
    int i = blockIdx.x * 256 + tid;
    int d = (i < N_NODES) ? deg[i] : 0;
    int v = d;
    lds[tid] = v;
    __syncthreads();
#pragma unroll
    for (int off = 1; off < 256; off <<= 1) {
        int t = (tid >= off) ? lds[tid - off] : 0;
        __syncthreads();
        v += t;
        lds[tid] = v;
        __syncthreads();
    }
    if (i < N_NODES) {
        locx[i] = v - d;                 // exclusive within block
        float df = (float)d + 1.0f;      // +1 self-loop
        dinv[i]   = rsqrtf(df);
        invdeg[i] = 1.0f / df;
    }
    if (tid == 255) bsum[blockIdx.x] = v;  // block total
}

__global__ __launch_bounds__(256) void scan_block_kernel(const int* __restrict__ bsum,
                                                         int* __restrict__ boff) {
    __shared__ int lds[256];
    int tid = threadIdx.x;
    int d = (tid < SCAN_G) ? bsum[tid] : 0;
    int v = d;
    lds[tid] = v;
    __syncthreads();
#pragma unroll
    for (int off = 1; off < 256; off <<= 1) {
        int t = (tid >= off) ? lds[tid - off] : 0;
        __syncthreads();
        v += t;
        lds[tid] = v;
        __syncthreads();
    }
    if (tid < SCAN_G) boff[tid] = v - d;   // exclusive block offsets
}

__global__ void scan_apply_kernel(const int* __restrict__ locx, const int* __restrict__ boff,
                                  int* __restrict__ startv) {
    int i = blockIdx.x * blockDim.x + threadIdx.x;
    if (i < N_NODES) startv[i] = locx[i] + boff[blockIdx.x];
}

// packed edge record: .x = src node, .y = float bits of norm
__global__ void csr_build_kernel(const int* __restrict__ src, const int* __restrict__ dst,
                                 const int* __restrict__ start, int* __restrict__ cursor,
                                 const float* __restrict__ dinv,
                                 int2* __restrict__ csr_pair) {
    int e = blockIdx.x * blockDim.x + threadIdx.x;
    if (e < N_EDGES) {
        int s = src[e], d = dst[e];
        int slot = start[d] + atomicAdd(&cursor[d], 1);
        int2 rec;
        rec.x = s;
        rec.y = __float_as_int(dinv[s] * dinv[d]);
        csr_pair[slot] = rec;
    }
}

// C[i][j] = sum_k A[i][k] * W[k][j].  Register-tiled: block = 64 rows x 128
// cols, 256 threads, each thread 8 rows x 4 cols (32 acc VGPRs).
__global__ __launch_bounds__(256) void gemm_kernel(const float* __restrict__ A,
                                                   const float* __restrict__ W,
                                                   float* __restrict__ C) {
    __shared__ float4 Alds[GR][DIM / 4];
    int row0 = blockIdx.x * GR;
    int tid  = threadIdx.x;
    for (int i = tid; i < GR * (DIM / 4); i += 256) {
        int r = i >> 5, c = i & 31;
        int gr = row0 + r;
        Alds[r][c] = (gr < N_NODES) ? ((const float4*)A)[(size_t)gr * 32 + c]
                                    : make_float4(0.f, 0.f, 0.f, 0.f);
    }
    __syncthreads();
    int tx = tid & 31;   // cols tx*4 .. tx*4+3
    int ty = tid >> 5;   // rows ty*8 .. ty*8+7
    float acc[8][4];
#pragma unroll
    for (int r = 0; r < 8; ++r)
#pragma unroll
        for (int c = 0; c < 4; ++c) acc[r][c] = 0.f;
    const float4* W4 = (const float4*)W;
    for (int k = 0; k < DIM; k += 4) {
        float4 a[8];
#pragma unroll
        for (int r = 0; r < 8; ++r) a[r] = Alds[ty * 8 + r][k >> 2];
        float4 w0 = W4[(k + 0) * 32 + tx];
        float4 w1 = W4[(k + 1) * 32 + tx];
        float4 w2 = W4[(k + 2) * 32 + tx];
        float4 w3 = W4[(k + 3) * 32 + tx];
#pragma unroll
        for (int r = 0; r < 8; ++r) {
            acc[r][0] += a[r].x * w0.x + a[r].y * w1.x + a[r].z * w2.x + a[r].w * w3.x;
            acc[r][1] += a[r].x * w0.y + a[r].y * w1.y + a[r].z * w2.y + a[r].w * w3.y;
            acc[r][2] += a[r].x * w0.z + a[r].y * w1.z + a[r].z * w2.z + a[r].w * w3.z;
            acc[r][3] += a[r].x * w0.w + a[r].y * w1.w + a[r].z * w2.w + a[r].w * w3.w;
        }
    }
#pragma unroll
    for (int r = 0; r < 8; ++r) {
        int gr = row0 + ty * 8 + r;
        if (gr < N_NODES) {
            float4 o = make_float4(acc[r][0], acc[r][1], acc[r][2], acc[r][3]);
            ((float4*)C)[(size_t)gr * 32 + tx] = o;
        }
    }
}

// One wave per (node, feature-half); lane handles 1 feature (float).
// half = blockIdx & 1 so round-robin block->XCD dispatch gives each XCD a
// 12.8MB gather footprint. Edge (src,norm) one-per-lane per 64-edge chunk,
// shfl-broadcast, 8 gathers in flight. No atomics. Reads only HW.
__global__ __launch_bounds__(256) void pull_kernel(const float* __restrict__ HW,
                                                   const int2* __restrict__ csr_pair,
                                                   const int* __restrict__ start,
                                                   const int* __restrict__ deg,
                                                   const float* __restrict__ invdeg,
                                                   const float* __restrict__ bias,
                                                   float* __restrict__ Fout) {
    int wid  = threadIdx.x >> 6;                 // 0..3
    int lane = threadIdx.x & 63;
    int half = blockIdx.x & 1;
    int node = (blockIdx.x >> 1) * 4 + wid;
    if (node >= N_NODES) return;
    int f = half * 64 + lane;                    // feature index
    int st = start[node];
    int dg = deg[node];
    float ax = 0.f;
    for (int base = 0; base < dg; base += 64) {
        int m = min(dg - base, 64);
        int2 rec = (lane < m) ? csr_pair[st + base + lane] : make_int2(0, 0);
        int   si = rec.x;
        float wi = __int_as_float(rec.y);
        int idx = 0;
        for (; idx + 8 <= m; idx += 8) {
            int s0 = __shfl(si, idx);     int s1 = __shfl(si, idx + 1);
            int s2 = __shfl(si, idx + 2); int s3 = __shfl(si, idx + 3);
            int s4 = __shfl(si, idx + 4); int s5 = __shfl(si, idx + 5);
            int s6 = __shfl(si, idx + 6); int s7 = __shfl(si, idx + 7);
            float w0 = __shfl(wi, idx);     float w1 = __shfl(wi, idx + 1);
            float w2 = __shfl(wi, idx + 2); float w3 = __shfl(wi, idx + 3);
            float w4 = __shfl(wi, idx + 4); float w5 = __shfl(wi, idx + 5);
            float w6 = __shfl(wi, idx + 6); float w7 = __shfl(wi, idx + 7);
            float v0 = HW[(size_t)s0 * DIM + f];
            float v1 = HW[(size_t)s1 * DIM + f];
            float v2 = HW[(size_t)s2 * DIM + f];
            float v3 = HW[(size_t)s3 * DIM + f];
            float v4 = HW[(size_t)s4 * DIM + f];
            float v5 = HW[(size_t)s5 * DIM + f];
            float v6 = HW[(size_t)s6 * DIM + f];
            float v7 = HW[(size_t)s7 * DIM + f];
            ax += v0 * w0 + v1 * w1 + v2 * w2 + v3 * w3
                + v4 * w4 + v5 * w5 + v6 * w6 + v7 * w7;
        }
        for (; idx < m; ++idx) {
            int s = __shfl(si, idx);
            float w = __shfl(wi, idx);
            ax += HW[(size_t)s * DIM + f] * w;
        }
    }
    ax += HW[(size_t)node * DIM + f] * invdeg[node];   // self-loop term
    ax = fmaxf(ax + bias[f], 0.f);
    Fout[(size_t)node * DIM + f] = ax;
}

// batch is sorted: graph g occupies [startg[g], endg[g]). Boundary detection.
__global__ void bounds_kernel(const int* __restrict__ batch,
                              int* __restrict__ startg, int* __restrict__ endg) {
    int i = blockIdx.x * blockDim.x + threadIdx.x;
    if (i >= N_NODES) return;
    int b = batch[i];
    if (i == 0 || batch[i - 1] != b) startg[b] = i;
    if (i == N_NODES - 1 || batch[i + 1] != b) endg[b] = i + 1;
}

// batch is sorted: run-length accumulate per thread-feature, flush on change.
__global__ __launch_bounds__(128) void pool_kernel(const float* __restrict__ F,
                                                   const int* __restrict__ batch,
                                                   float* __restrict__ pooled) {
    int s0 = blockIdx.x * STRIP;
    int f  = threadIdx.x;
    if (s0 >= N_NODES) return;
    int end = min(s0 + STRIP, N_NODES);
    int cur = batch[s0];
    float acc = 0.f;
    for (int n = s0; n < end; ++n) {
        int bn = batch[n];              // block-uniform
        if (bn != cur) {
            atomicAdd(&pooled[cur * DIM + f], acc);
            acc = 0.f; cur = bn;
        }
        acc += F[(size_t)n * DIM + f];  // coalesced 512B per n
    }
    atomicAdd(&pooled[cur * DIM + f], acc);
}

__global__ __launch_bounds__(640) void fc_kernel(const float* __restrict__ pooled,
                                                 const int* __restrict__ startg,
                                                 const int* __restrict__ endg,
                                                 const float* __restrict__ Wfc,
                                                 const float* __restrict__ bfc,
                                                 float* __restrict__ out) {
    int t = threadIdx.x;
    if (t >= N_GRAPHS * OUT_DIM) return;
    int g = t / OUT_DIM, o = t % OUT_DIM;
    int c = endg[g] - startg[g];
    float inv = 1.0f / fmaxf((float)c, 1.0f);
    float acc = bfc[o];
#pragma unroll 8
    for (int k = 0; k < DIM; ++k)
        acc += pooled[g * DIM + k] * inv * Wfc[k * OUT_DIM + o];
    out[g * OUT_DIM + o] = acc;
}

extern "C" void kernel_launch(void* const* d_in, const int* in_sizes, int n_in,
                              void* d_out, int out_size, void* d_ws, size_t ws_size,
                              hipStream_t stream) {
    const float* x    = (const float*)d_in[0];
    const int*   ei   = (const int*)d_in[1];     // [2, E]
    const int*   batch= (const int*)d_in[2];
    const float* W1   = (const float*)d_in[3];
    const float* b1   = (const float*)d_in[4];
    const float* W2   = (const float*)d_in[5];
    const float* b2   = (const float*)d_in[6];
    const float* W3   = (const float*)d_in[7];
    const float* b3   = (const float*)d_in[8];
    const float* Wfc  = (const float*)d_in[9];
    const float* bfc  = (const float*)d_in[10];
    float* out = (float*)d_out;

    const int* src = ei;
    const int* dst = ei + N_EDGES;

    // workspace layout (4-byte elements), ~58 MB total
    char* ws = (char*)d_ws;
    size_t o = 0;
    float* HW   = (float*)(ws + o); o += (size_t)N_NODES * DIM * 4;   // GEMM out
    float* PB   = (float*)(ws + o); o += (size_t)N_NODES * DIM * 4;   // pull out / GEMM in
    // ---- zeroed region start ----
    int*   deg    = (int*)(ws + o); o += (size_t)N_NODES * 4;
    int*   cursor = (int*)(ws + o); o += (size_t)N_NODES * 4;
    float* pooled = (float*)(ws + o); o += (size_t)N_GRAPHS * DIM * 4;
    int*   startg = (int*)(ws + o); o += (size_t)N_GRAPHS * 4;
    int*   endg   = (int*)(ws + o); o += (size_t)N_GRAPHS * 4;
    // ---- zeroed region end ----
    int*   startv = (int*)(ws + o); o += (size_t)N_NODES * 4;
    float* dinv   = (float*)(ws + o); o += (size_t)N_NODES * 4;
    float* invdeg = (float*)(ws + o); o += (size_t)N_NODES * 4;
    int*   locx   = (int*)(ws + o); o += (size_t)N_NODES * 4;
    int*   bsum   = (int*)(ws + o); o += (size_t)SCAN_G * 4;
    int*   boff   = (int*)(ws + o); o += (size_t)SCAN_G * 4;
    o = (o + 7) & ~(size_t)7;  // align for int2
    int2*  csr_pair = (int2*)(ws + o); o += (size_t)N_EDGES * 8;

    const int nzero = 2 * N_NODES + N_GRAPHS * DIM + 2 * N_GRAPHS;

    zero_kernel<<<(nzero + 255) / 256, 256, 0, stream>>>(deg, nzero);
    hist_kernel<<<(N_EDGES + 255) / 256, 256, 0, stream>>>(dst, deg);
    scan_local_kernel<<<SCAN_G, 256, 0, stream>>>(deg, locx, bsum, dinv, invdeg);
    scan_block_kernel<<<1, 256, 0, stream>>>(bsum, boff);
    scan_apply_kernel<<<SCAN_G, 256, 0, stream>>>(locx, boff, startv);
    csr_build_kernel<<<(N_EDGES + 255) / 256, 256, 0, stream>>>(src, dst, startv, cursor,
                                                                dinv, csr_pair);

    const int ggrid = (N_NODES + GR - 1) / GR;
    const int pgrid = 2 * ((N_NODES + 3) / 4);   // x2: feature halves

    // layer 1: x -> HW -> PB
    gemm_kernel<<<ggrid, 256, 0, stream>>>(x, W1, HW);
    pull_kernel<<<pgrid, 256, 0, stream>>>(HW, csr_pair, startv, deg, invdeg, b1, PB);
    // layer 2: PB -> HW -> PB  (pull reads only HW, safe to overwrite PB)
    gemm_kernel<<<ggrid, 256, 0, stream>>>(PB, W2, HW);
    pull_kernel<<<pgrid, 256, 0, stream>>>(HW, csr_pair, startv, deg, invdeg, b2, PB);
    // layer 3: PB -> HW -> PB
    gemm_kernel<<<ggrid, 256, 0, stream>>>(PB, W3, HW);
    pull_kernel<<<pgrid, 256, 0, stream>>>(HW, csr_pair, startv, deg, invdeg, b3, PB);

    bounds_kernel<<<(N_NODES + 255) / 256, 256, 0, stream>>>(batch, startg, endg);
    pool_kernel<<<(N_NODES + STRIP - 1) / STRIP, 128, 0, stream>>>(PB, batch, pooled);
    fc_kernel<<<1, 640, 0, stream>>>(pooled, startg, endg, Wfc, bfc, out);
}

// Round 16
// 437.025 us; speedup vs baseline: 1.0709x; 1.0709x over previous
//
#include <hip/hip_runtime.h>

// GCN: 3x (GEMM -> normalized edge aggregation -> +self +bias +ReLU),
// then global mean pool over 64 graphs, then FC [128 -> 10].
// R12 lessons: feature-half split REGRESSED pull 47.6->59.6us (doubled VMEM
// instr + shfl work; L2-footprint win too small). Reverted. New pull: paired
// edges — lanes 0-31 even edge, lanes 32-63 odd edge, float4/lane = 1024B
// per gather instruction (2 edges), half the loads+shfls of the R6 form.
// Prep: deg histogram -> 3-dispatch exclusive scan (no atomics) -> CSR build.

#define N_NODES 50000
#define N_EDGES 600000
#define DIM 128      // IN == H == 128
#define OUT_DIM 10
#define N_GRAPHS 64
#define STRIP 128    // pool rows per block
#define GR 64        // gemm rows per block
#define SCAN_G ((N_NODES + 255) / 256)   // 196 scan blocks

__global__ void zero_kernel(int* __restrict__ p, int n) {
    int i = blockIdx.x * blockDim.x + threadIdx.x;
    for (; i < n; i += gridDim.x * blockDim.x) p[i] = 0;
}

// in-degree histogram over dst (random addresses across 200KB, L2-resident)
__global__ void hist_kernel(const int* __restrict__ dst, int* __restrict__ deg) {
    int e = blockIdx.x * blockDim.x + threadIdx.x;
    if (e < N_EDGES) atomicAdd(&deg[dst[e]], 1);
}

// --- exclusive prefix sum of deg (3 dispatches, no atomics) ---
__global__ __launch_bounds__(256) void scan_local_kernel(const int* __restrict__ deg,
                                                         int* __restrict__ locx,
                                                         int* __restrict__ bsum,
                                                         float* __restrict__ dinv,
                                                         float* __restrict__ invdeg) {
    __shared__ int lds[256];
    int tid = threadIdx.x;
    int i = blockIdx.x * 256 + tid;
    int d = (i < N_NODES) ? deg[i] : 0;
    int v = d;
    lds[tid] = v;
    __syncthreads();
#pragma unroll
    for (int off = 1; off < 256; off <<= 1) {
        int t = (tid >= off) ? lds[tid - off] : 0;
        __syncthreads();
        v += t;
        lds[tid] = v;
        __syncthreads();
    }
    if (i < N_NODES) {
        locx[i] = v - d;                 // exclusive within block
        float df = (float)d + 1.0f;      // +1 self-loop
        dinv[i]   = rsqrtf(df);
        invdeg[i] = 1.0f / df;
    }
    if (tid == 255) bsum[blockIdx.x] = v;  // block total
}

__global__ __launch_bounds__(256) void scan_block_kernel(const int* __restrict__ bsum,
                                                         int* __restrict__ boff) {
    __shared__ int lds[256];
    int tid = threadIdx.x;
    int d = (tid < SCAN_G) ? bsum[tid] : 0;
    int v = d;
    lds[tid] = v;
    __syncthreads();
#pragma unroll
    for (int off = 1; off < 256; off <<= 1) {
        int t = (tid >= off) ? lds[tid - off] : 0;
        __syncthreads();
        v += t;
        lds[tid] = v;
        __syncthreads();
    }
    if (tid < SCAN_G) boff[tid] = v - d;   // exclusive block offsets
}

__global__ void scan_apply_kernel(const int* __restrict__ locx, const int* __restrict__ boff,
                                  int* __restrict__ startv) {
    int i = blockIdx.x * blockDim.x + threadIdx.x;
    if (i < N_NODES) startv[i] = locx[i] + boff[blockIdx.x];
}

// packed edge record: .x = src node, .y = float bits of norm
__global__ void csr_build_kernel(const int* __restrict__ src, const int* __restrict__ dst,
                                 const int* __restrict__ start, int* __restrict__ cursor,
                                 const float* __restrict__ dinv,
                                 int2* __restrict__ csr_pair) {
    int e = blockIdx.x * blockDim.x + threadIdx.x;
    if (e < N_EDGES) {
        int s = src[e], d = dst[e];
        int slot = start[d] + atomicAdd(&cursor[d], 1);
        int2 rec;
        rec.x = s;
        rec.y = __float_as_int(dinv[s] * dinv[d]);
        csr_pair[slot] = rec;
    }
}

// C[i][j] = sum_k A[i][k] * W[k][j].  Register-tiled: block = 64 rows x 128
// cols, 256 threads, each thread 8 rows x 4 cols (32 acc VGPRs).
__global__ __launch_bounds__(256) void gemm_kernel(const float* __restrict__ A,
                                                   const float* __restrict__ W,
                                                   float* __restrict__ C) {
    __shared__ float4 Alds[GR][DIM / 4];
    int row0 = blockIdx.x * GR;
    int tid  = threadIdx.x;
    for (int i = tid; i < GR * (DIM / 4); i += 256) {
        int r = i >> 5, c = i & 31;
        int gr = row0 + r;
        Alds[r][c] = (gr < N_NODES) ? ((const float4*)A)[(size_t)gr * 32 + c]
                                    : make_float4(0.f, 0.f, 0.f, 0.f);
    }
    __syncthreads();
    int tx = tid & 31;   // cols tx*4 .. tx*4+3
    int ty = tid >> 5;   // rows ty*8 .. ty*8+7
    float acc[8][4];
#pragma unroll
    for (int r = 0; r < 8; ++r)
#pragma unroll
        for (int c = 0; c < 4; ++c) acc[r][c] = 0.f;
    const float4* W4 = (const float4*)W;
    for (int k = 0; k < DIM; k += 4) {
        float4 a[8];
#pragma unroll
        for (int r = 0; r < 8; ++r) a[r] = Alds[ty * 8 + r][k >> 2];
        float4 w0 = W4[(k + 0) * 32 + tx];
        float4 w1 = W4[(k + 1) * 32 + tx];
        float4 w2 = W4[(k + 2) * 32 + tx];
        float4 w3 = W4[(k + 3) * 32 + tx];
#pragma unroll
        for (int r = 0; r < 8; ++r) {
            acc[r][0] += a[r].x * w0.x + a[r].y * w1.x + a[r].z * w2.x + a[r].w * w3.x;
            acc[r][1] += a[r].x * w0.y + a[r].y * w1.y + a[r].z * w2.y + a[r].w * w3.y;
            acc[r][2] += a[r].x * w0.z + a[r].y * w1.z + a[r].z * w2.z + a[r].w * w3.z;
            acc[r][3] += a[r].x * w0.w + a[r].y * w1.w + a[r].z * w2.w + a[r].w * w3.w;
        }
    }
#pragma unroll
    for (int r = 0; r < 8; ++r) {
        int gr = row0 + ty * 8 + r;
        if (gr < N_NODES) {
            float4 o = make_float4(acc[r][0], acc[r][1], acc[r][2], acc[r][3]);
            ((float4*)C)[(size_t)gr * 32 + tx] = o;
        }
    }
}

// One wave per node. PAIRED edges: lanes 0-31 handle even edges, lanes 32-63
// odd edges; each lane loads float4 (features 4l..4l+3 of its edge's src row)
// -> one 1024B gather instruction covers 2 edges. Per 8 edges: 4 loads +
// 8 bpermutes (vs 8 loads + 16 shfls in the R6 float2 form). Cross-half
// combine via shfl at the end. No atomics; reads only HW.
__global__ __launch_bounds__(256) void pull_kernel(const float* __restrict__ HW,
                                                   const int2* __restrict__ csr_pair,
                                                   const int* __restrict__ start,
                                                   const int* __restrict__ deg,
                                                   const float* __restrict__ invdeg,
                                                   const float* __restrict__ bias,
                                                   float* __restrict__ Fout) {
    int wid  = threadIdx.x >> 6;                 // 0..3
    int lane = threadIdx.x & 63;
    int node = blockIdx.x * 4 + wid;
    if (node >= N_NODES) return;
    int hi = lane >> 5;                          // 0: even edge of pair, 1: odd
    int l  = lane & 31;                          // feature quad: 4l..4l+3
    const float4* HW4 = (const float4*)HW;
    int st = start[node];
    int dg = deg[node];
    // hoist self-loop row + bias early for extra MLP
    float  iv = invdeg[node];
    float4 hs = HW4[(size_t)node * 32 + l];
    float4 bb = ((const float4*)bias)[l];
    float4 acc = make_float4(0.f, 0.f, 0.f, 0.f);
    for (int base = 0; base < dg; base += 64) {
        int m = min(dg - base, 64);
        int2 rec = (lane < m) ? csr_pair[st + base + lane] : make_int2(0, 0);
        int   si = rec.x;                        // lane>=m: si=0, wi=0 (safe pad)
        float wi = __int_as_float(rec.y);
        int npair = (m + 1) >> 1;
        int p = 0;
        for (; p + 4 <= npair; p += 4) {
            int i0 = 2 * (p + 0) + hi, i1 = 2 * (p + 1) + hi;
            int i2 = 2 * (p + 2) + hi, i3 = 2 * (p + 3) + hi;
            int s0 = __shfl(si, i0), s1 = __shfl(si, i1);
            int s2 = __shfl(si, i2), s3 = __shfl(si, i3);
            float w0 = __shfl(wi, i0), w1 = __shfl(wi, i1);
            float w2 = __shfl(wi, i2), w3 = __shfl(wi, i3);
            float4 v0 = HW4[(size_t)s0 * 32 + l];
            float4 v1 = HW4[(size_t)s1 * 32 + l];
            float4 v2 = HW4[(size_t)s2 * 32 + l];
            float4 v3 = HW4[(size_t)s3 * 32 + l];
            acc.x += v0.x * w0; acc.y += v0.y * w0; acc.z += v0.z * w0; acc.w += v0.w * w0;
            acc.x += v1.x * w1; acc.y += v1.y * w1; acc.z += v1.z * w1; acc.w += v1.w * w1;
            acc.x += v2.x * w2; acc.y += v2.y * w2; acc.z += v2.z * w2; acc.w += v2.w * w2;
            acc.x += v3.x * w3; acc.y += v3.y * w3; acc.z += v3.z * w3; acc.w += v3.w * w3;
        }
        for (; p < npair; ++p) {
            int i0 = 2 * p + hi;                 // if m odd, i0==m reads zero pad
            int s0 = __shfl(si, i0);
            float w0 = __shfl(wi, i0);
            float4 v0 = HW4[(size_t)s0 * 32 + l];
            acc.x += v0.x * w0; acc.y += v0.y * w0; acc.z += v0.z * w0; acc.w += v0.w * w0;
        }
    }
    // combine halves: lane i (<32) accumulates lane i+32's partial
    acc.x += __shfl(acc.x, lane + 32);
    acc.y += __shfl(acc.y, lane + 32);
    acc.z += __shfl(acc.z, lane + 32);
    acc.w += __shfl(acc.w, lane + 32);
    if (lane < 32) {
        acc.x += hs.x * iv; acc.y += hs.y * iv;  // self-loop term h * (1/deg)
        acc.z += hs.z * iv; acc.w += hs.w * iv;
        acc.x = fmaxf(acc.x + bb.x, 0.f);
        acc.y = fmaxf(acc.y + bb.y, 0.f);
        acc.z = fmaxf(acc.z + bb.z, 0.f);
        acc.w = fmaxf(acc.w + bb.w, 0.f);
        ((float4*)Fout)[(size_t)node * 32 + l] = acc;
    }
}

// batch is sorted: graph g occupies [startg[g], endg[g]). Boundary detection.
__global__ void bounds_kernel(const int* __restrict__ batch,
                              int* __restrict__ startg, int* __restrict__ endg) {
    int i = blockIdx.x * blockDim.x + threadIdx.x;
    if (i >= N_NODES) return;
    int b = batch[i];
    if (i == 0 || batch[i - 1] != b) startg[b] = i;
    if (i == N_NODES - 1 || batch[i + 1] != b) endg[b] = i + 1;
}

// batch is sorted: run-length accumulate per thread-feature, flush on change.
__global__ __launch_bounds__(128) void pool_kernel(const float* __restrict__ F,
                                                   const int* __restrict__ batch,
                                                   float* __restrict__ pooled) {
    int s0 = blockIdx.x * STRIP;
    int f  = threadIdx.x;
    if (s0 >= N_NODES) return;
    int end = min(s0 + STRIP, N_NODES);
    int cur = batch[s0];
    float acc = 0.f;
    for (int n = s0; n < end; ++n) {
        int bn = batch[n];              // block-uniform
        if (bn != cur) {
            atomicAdd(&pooled[cur * DIM + f], acc);
            acc = 0.f; cur = bn;
        }
        acc += F[(size_t)n * DIM + f];  // coalesced 512B per n
    }
    atomicAdd(&pooled[cur * DIM + f], acc);
}

__global__ __launch_bounds__(640) void fc_kernel(const float* __restrict__ pooled,
                                                 const int* __restrict__ startg,
                                                 const int* __restrict__ endg,
                                                 const float* __restrict__ Wfc,
                                                 const float* __restrict__ bfc,
                                                 float* __restrict__ out) {
    int t = threadIdx.x;
    if (t >= N_GRAPHS * OUT_DIM) return;
    int g = t / OUT_DIM, o = t % OUT_DIM;
    int c = endg[g] - startg[g];
    float inv = 1.0f / fmaxf((float)c, 1.0f);
    float acc = bfc[o];
#pragma unroll 8
    for (int k = 0; k < DIM; ++k)
        acc += pooled[g * DIM + k] * inv * Wfc[k * OUT_DIM + o];
    out[g * OUT_DIM + o] = acc;
}

extern "C" void kernel_launch(void* const* d_in, const int* in_sizes, int n_in,
                              void* d_out, int out_size, void* d_ws, size_t ws_size,
                              hipStream_t stream) {
    const float* x    = (const float*)d_in[0];
    const int*   ei   = (const int*)d_in[1];     // [2, E]
    const int*   batch= (const int*)d_in[2];
    const float* W1   = (const float*)d_in[3];
    const float* b1   = (const float*)d_in[4];
    const float* W2   = (const float*)d_in[5];
    const float* b2   = (const float*)d_in[6];
    const float* W3   = (const float*)d_in[7];
    const float* b3   = (const float*)d_in[8];
    const float* Wfc  = (const float*)d_in[9];
    const float* bfc  = (const float*)d_in[10];
    float* out = (float*)d_out;

    const int* src = ei;
    const int* dst = ei + N_EDGES;

    // workspace layout (4-byte elements), ~58 MB total
    char* ws = (char*)d_ws;
    size_t o = 0;
    float* HW   = (float*)(ws + o); o += (size_t)N_NODES * DIM * 4;   // GEMM out
    float* PB   = (float*)(ws + o); o += (size_t)N_NODES * DIM * 4;   // pull out / GEMM in
    // ---- zeroed region start ----
    int*   deg    = (int*)(ws + o); o += (size_t)N_NODES * 4;
    int*   cursor = (int*)(ws + o); o += (size_t)N_NODES * 4;
    float* pooled = (float*)(ws + o); o += (size_t)N_GRAPHS * DIM * 4;
    int*   startg = (int*)(ws + o); o += (size_t)N_GRAPHS * 4;
    int*   endg   = (int*)(ws + o); o += (size_t)N_GRAPHS * 4;
    // ---- zeroed region end ----
    int*   startv = (int*)(ws + o); o += (size_t)N_NODES * 4;
    float* dinv   = (float*)(ws + o); o += (size_t)N_NODES * 4;
    float* invdeg = (float*)(ws + o); o += (size_t)N_NODES * 4;
    int*   locx   = (int*)(ws + o); o += (size_t)N_NODES * 4;
    int*   bsum   = (int*)(ws + o); o += (size_t)SCAN_G * 4;
    int*   boff   = (int*)(ws + o); o += (size_t)SCAN_G * 4;
    o = (o + 7) & ~(size_t)7;  // align for int2
    int2*  csr_pair = (int2*)(ws + o); o += (size_t)N_EDGES * 8;

    const int nzero = 2 * N_NODES + N_GRAPHS * DIM + 2 * N_GRAPHS;

    zero_kernel<<<(nzero + 255) / 256, 256, 0, stream>>>(deg, nzero);
    hist_kernel<<<(N_EDGES + 255) / 256, 256, 0, stream>>>(dst, deg);
    scan_local_kernel<<<SCAN_G, 256, 0, stream>>>(deg, locx, bsum, dinv, invdeg);
    scan_block_kernel<<<1, 256, 0, stream>>>(bsum, boff);
    scan_apply_kernel<<<SCAN_G, 256, 0, stream>>>(locx, boff, startv);
    csr_build_kernel<<<(N_EDGES + 255) / 256, 256, 0, stream>>>(src, dst, startv, cursor,
                                                                dinv, csr_pair);

    const int ggrid = (N_NODES + GR - 1) / GR;
    const int pgrid = (N_NODES + 3) / 4;

    // layer 1: x -> HW -> PB
    gemm_kernel<<<ggrid, 256, 0, stream>>>(x, W1, HW);
    pull_kernel<<<pgrid, 256, 0, stream>>>(HW, csr_pair, startv, deg, invdeg, b1, PB);
    // layer 2: PB -> HW -> PB  (pull reads only HW, safe to overwrite PB)
    gemm_kernel<<<ggrid, 256, 0, stream>>>(PB, W2, HW);
    pull_kernel<<<pgrid, 256, 0, stream>>>(HW, csr_pair, startv, deg, invdeg, b2, PB);
    // layer 3: PB -> HW -> PB
    gemm_kernel<<<ggrid, 256, 0, stream>>>(PB, W3, HW);
    pull_kernel<<<pgrid, 256, 0, stream>>>(HW, csr_pair, startv, deg, invdeg, b3, PB);

    bounds_kernel<<<(N_NODES + 255) / 256, 256, 0, stream>>>(batch, startg, endg);
    pool_kernel<<<(N_NODES + STRIP - 1) / STRIP, 128, 0, stream>>>(PB, batch, pooled);
    fc_kernel<<<1, 640, 0, stream>>>(pooled, startg, endg, Wfc, bfc, out);
}